// Round 1
// baseline (444.660 us; speedup 1.0000x reference)
//
#include <hip/hip_runtime.h>
#include <hip/hip_bf16.h>

#define DM 1024
#define BS 4
#define SS 1024
#define NH 16

typedef __attribute__((ext_vector_type(8))) short bf16x8;
typedef __attribute__((ext_vector_type(4))) float f32x4;

__device__ inline unsigned short f2bf(float x) {
    union { float f; unsigned u; } v; v.f = x;
    unsigned r = v.u + 0x7fffu + ((v.u >> 16) & 1u);
    return (unsigned short)(r >> 16);
}

template<typename T> __device__ inline void fetch4(const T* p, unsigned short* d);
template<> __device__ inline void fetch4<float>(const float* p, unsigned short* d) {
    float4 v = *reinterpret_cast<const float4*>(p);
    d[0] = f2bf(v.x); d[1] = f2bf(v.y); d[2] = f2bf(v.z); d[3] = f2bf(v.w);
}
template<> __device__ inline void fetch4<unsigned short>(const unsigned short* p, unsigned short* d) {
    *reinterpret_cast<uint2*>(d) = *reinterpret_cast<const uint2*>(p);
}

template<typename T> __device__ inline void store1(T* p, float v);
template<> __device__ inline void store1<float>(float* p, float v) { *p = v; }
template<> __device__ inline void store1<unsigned short>(unsigned short* p, float v) { *p = f2bf(v); }

// C[M,N] = scale * (A[M,K] @ B[N,K]^T) + bias[N]
// batched: z -> (zb, zh) offsets; A/B rows contiguous along K (both read identically).
template<int BM, int BN, int WR, int WC, typename TA, typename TB, typename TO>
__global__ __launch_bounds__(256) void gemm_abt(
    const TA* __restrict__ A, int lda, long long sAb, long long sAh,
    const TB* __restrict__ B, int ldb, long long sBb, long long sBh,
    TO* __restrict__ C, int ldc, long long sCb, long long sCh,
    const float* __restrict__ bias, int K, int H, float scale)
{
    constexpr int LDK = 40;              // padded LDS row stride (bf16 elems): 80B, 16B-aligned
    constexpr int MF = BM / WR / 16;     // 16x16 fragments per wave (M)
    constexpr int NF = BN / WC / 16;     // 16x16 fragments per wave (N)
    __shared__ unsigned short lA[BM * LDK];
    __shared__ unsigned short lB[BN * LDK];

    const int tid = threadIdx.x;
    const int z = blockIdx.z;
    const int zb = z / H, zh = z % H;
    const TA* Ap = A + sAb * zb + sAh * zh + (long long)blockIdx.y * BM * lda;
    const TB* Bp = B + sBb * zb + sBh * zh + (long long)blockIdx.x * BN * ldb;
    TO* Cp = C + sCb * zb + sCh * zh + (long long)blockIdx.y * BM * ldc + (long long)blockIdx.x * BN;

    const int wid = tid >> 6, lane = tid & 63;
    const int wr = wid / WC, wc = wid % WC;
    const int r0 = lane & 15;
    const int kq = (lane >> 4) * 8;

    f32x4 acc[MF][NF];
    #pragma unroll
    for (int m = 0; m < MF; ++m)
        #pragma unroll
        for (int n = 0; n < NF; ++n)
            acc[m][n] = f32x4{0.f, 0.f, 0.f, 0.f};

    for (int kt = 0; kt < K; kt += 32) {
        __syncthreads();
        // stage A tile: BM x 32 (fp32 or bf16 source -> bf16 LDS)
        #pragma unroll
        for (int qi = 0; qi < BM * 8 / 256; ++qi) {
            int idx = tid + qi * 256;
            int row = idx >> 3, c4 = idx & 7;
            unsigned short tmp[4];
            fetch4<TA>(Ap + (long long)row * lda + kt + c4 * 4, tmp);
            *reinterpret_cast<uint2*>(&lA[row * LDK + c4 * 4]) = *reinterpret_cast<const uint2*>(tmp);
        }
        // stage B tile: BN x 32
        #pragma unroll
        for (int qi = 0; qi < BN * 8 / 256; ++qi) {
            int idx = tid + qi * 256;
            int row = idx >> 3, c4 = idx & 7;
            unsigned short tmp[4];
            fetch4<TB>(Bp + (long long)row * ldb + kt + c4 * 4, tmp);
            *reinterpret_cast<uint2*>(&lB[row * LDK + c4 * 4]) = *reinterpret_cast<const uint2*>(tmp);
        }
        __syncthreads();

        bf16x8 af[MF], bfr[NF];
        #pragma unroll
        for (int m = 0; m < MF; ++m)
            af[m] = *reinterpret_cast<const bf16x8*>(&lA[(wr * MF * 16 + m * 16 + r0) * LDK + kq]);
        #pragma unroll
        for (int n = 0; n < NF; ++n)
            bfr[n] = *reinterpret_cast<const bf16x8*>(&lB[(wc * NF * 16 + n * 16 + r0) * LDK + kq]);
        #pragma unroll
        for (int m = 0; m < MF; ++m)
            #pragma unroll
            for (int n = 0; n < NF; ++n)
                acc[m][n] = __builtin_amdgcn_mfma_f32_16x16x32_bf16(af[m], bfr[n], acc[m][n], 0, 0, 0);
    }

    // epilogue: D layout col=lane&15, row=(lane>>4)*4+j  [verified m89/m91]
    const int cf = lane & 15, rf = (lane >> 4) * 4;
    #pragma unroll
    for (int m = 0; m < MF; ++m) {
        #pragma unroll
        for (int n = 0; n < NF; ++n) {
            int col = wc * NF * 16 + n * 16 + cf;
            float bv = bias ? bias[blockIdx.x * BN + col] : 0.0f;
            #pragma unroll
            for (int j = 0; j < 4; ++j) {
                int row = wr * MF * 16 + m * 16 + rf + j;
                store1<TO>(&Cp[(long long)row * ldc + col], acc[m][n][j] * scale + bv);
            }
        }
    }
}

// vT[(b*NH+h)*64 + d][t] = v_p[b][t][h*64+d]   (bf16 -> bf16)
__global__ __launch_bounds__(256) void transpose_vh(const unsigned short* __restrict__ vp,
                                                    unsigned short* __restrict__ vT)
{
    __shared__ unsigned short tile[64][65];
    const int bh = blockIdx.y;
    const int b = bh >> 4, h = bh & 15;
    const long long t0 = (long long)blockIdx.x * 64;
    const int tid = threadIdx.x;
    #pragma unroll
    for (int kk = 0; kk < 4; ++kk) {
        int l = tid + kk * 256;
        int row = l >> 4, c4 = l & 15;
        const unsigned short* src = vp + ((long long)b * SS + t0 + row) * DM + h * 64 + c4 * 4;
        ushort4 val = *reinterpret_cast<const ushort4*>(src);
        tile[row][c4 * 4 + 0] = val.x;
        tile[row][c4 * 4 + 1] = val.y;
        tile[row][c4 * 4 + 2] = val.z;
        tile[row][c4 * 4 + 3] = val.w;
    }
    __syncthreads();
    #pragma unroll
    for (int kk = 0; kk < 4; ++kk) {
        int l = tid + kk * 256;
        int d = l >> 4, i4 = l & 15;
        ushort4 o;
        o.x = tile[i4 * 4 + 0][d];
        o.y = tile[i4 * 4 + 1][d];
        o.z = tile[i4 * 4 + 2][d];
        o.w = tile[i4 * 4 + 3][d];
        *reinterpret_cast<ushort4*>(vT + ((long long)bh * 64 + d) * SS + t0 + i4 * 4) = o;
    }
}

// in-place row softmax over 1024 fp32 elements per row
__global__ __launch_bounds__(256) void softmax_rows(float* __restrict__ p)
{
    float* r = p + (long long)blockIdx.x * 1024;
    const int tid = threadIdx.x;
    float4 v = reinterpret_cast<float4*>(r)[tid];
    float m = fmaxf(fmaxf(v.x, v.y), fmaxf(v.z, v.w));
    #pragma unroll
    for (int off = 32; off > 0; off >>= 1) m = fmaxf(m, __shfl_xor(m, off));
    __shared__ float sred[8];
    if ((tid & 63) == 0) sred[tid >> 6] = m;
    __syncthreads();
    m = fmaxf(fmaxf(sred[0], sred[1]), fmaxf(sred[2], sred[3]));
    float e0 = expf(v.x - m), e1 = expf(v.y - m), e2 = expf(v.z - m), e3 = expf(v.w - m);
    float s = e0 + e1 + e2 + e3;
    #pragma unroll
    for (int off = 32; off > 0; off >>= 1) s += __shfl_xor(s, off);
    if ((tid & 63) == 0) sred[4 + (tid >> 6)] = s;
    __syncthreads();
    s = sred[4] + sred[5] + sred[6] + sred[7];
    float inv = 1.0f / s;
    float4 o; o.x = e0 * inv; o.y = e1 * inv; o.z = e2 * inv; o.w = e3 * inv;
    reinterpret_cast<float4*>(r)[tid] = o;
}

extern "C" void kernel_launch(void* const* d_in, const int* in_sizes, int n_in,
                              void* d_out, int out_size, void* d_ws, size_t ws_size,
                              hipStream_t stream) {
    (void)in_sizes; (void)n_in; (void)out_size; (void)ws_size;
    const float* v    = (const float*)d_in[0];
    // d_in[1] = k : unused by the reference (bug preserved)
    const float* q    = (const float*)d_in[2];
    const float* wq_w = (const float*)d_in[3];
    const float* wq_b = (const float*)d_in[4];
    const float* wv_w = (const float*)d_in[5];
    const float* wv_b = (const float*)d_in[6];
    const float* dw   = (const float*)d_in[7];
    const float* db   = (const float*)d_in[8];

    // workspace: 5 x 4M bf16 = 40 MB
    unsigned short* q_p = (unsigned short*)d_ws;
    unsigned short* v_p = q_p + (4 << 20);
    unsigned short* k_p = v_p + (4 << 20);
    unsigned short* vT  = k_p + (4 << 20);
    unsigned short* cc  = vT  + (4 << 20);

    float* out0   = (float*)d_out;
    float* logits = out0 + (long long)BS * SS * DM;   // d_out region 2 (attention_weights), used as fp32 logits scratch

    dim3 blk(256);

    // q_p = q @ wq^T + bq   [4096x1024] <- [4096x1024]x[1024x1024]
    gemm_abt<128,128,2,2,float,float,unsigned short><<<dim3(8,32,1),blk,0,stream>>>(
        q, DM, 0, 0, wq_w, DM, 0, 0, q_p, DM, 0, 0, wq_b, DM, 1, 1.0f);
    // v_p = v @ wv^T + bv
    gemm_abt<128,128,2,2,float,float,unsigned short><<<dim3(8,32,1),blk,0,stream>>>(
        v, DM, 0, 0, wv_w, DM, 0, 0, v_p, DM, 0, 0, wv_b, DM, 1, 1.0f);
    // k_p = v_p @ wv^T + bv
    gemm_abt<128,128,2,2,unsigned short,float,unsigned short><<<dim3(8,32,1),blk,0,stream>>>(
        v_p, DM, 0, 0, wv_w, DM, 0, 0, k_p, DM, 0, 0, wv_b, DM, 1, 1.0f);
    // vT per-head transpose of v_p
    transpose_vh<<<dim3(16,64),blk,0,stream>>>(v_p, vT);
    // logits[b,h] = q_p[b,:,h*64:] @ k_p[b,:,h*64:]^T / 8   -> fp32 into d_out region2
    gemm_abt<128,128,2,2,unsigned short,unsigned short,float><<<dim3(8,8,64),blk,0,stream>>>(
        q_p, DM, (long long)SS*DM, 64,
        k_p, DM, (long long)SS*DM, 64,
        logits, SS, (long long)NH*SS*SS, (long long)SS*SS,
        nullptr, 64, NH, 0.125f);
    // cc[b,:,h*64:] = logits[b,h] @ vh  (raw logits, bug preserved);  vT rows are [d][t], K=t
    gemm_abt<128,64,4,1,float,unsigned short,unsigned short><<<dim3(1,8,64),blk,0,stream>>>(
        logits, SS, (long long)NH*SS*SS, (long long)SS*SS,
        vT, SS, (long long)NH*64*SS, (long long)64*SS,
        cc, DM, (long long)SS*DM, 64,
        nullptr, SS, NH, 1.0f);
    // softmax in place on region2 (after attn consumed raw logits)
    softmax_rows<<<dim3(BS*NH*SS),blk,0,stream>>>(logits);
    // out = cc @ dense^T + db
    gemm_abt<128,128,2,2,unsigned short,float,float><<<dim3(8,32,1),blk,0,stream>>>(
        cc, DM, 0, 0, dw, DM, 0, 0, out0, DM, 0, 0, db, DM, 1, 1.0f);
}

// Round 4
// 372.704 us; speedup vs baseline: 1.1931x; 1.1931x over previous
//
#include <hip/hip_runtime.h>
#include <hip/hip_bf16.h>

#define DM 1024
#define BS 4
#define SS 1024
#define NH 16

typedef __attribute__((ext_vector_type(8))) short bf16x8;
typedef __attribute__((ext_vector_type(4))) float f32x4;

__device__ inline unsigned short f2bf(float x) {
    union { float f; unsigned u; } v; v.f = x;
    unsigned r = v.u + 0x7fffu + ((v.u >> 16) & 1u);
    return (unsigned short)(r >> 16);
}

template<typename T> __device__ inline void fetch4(const T* p, unsigned short* d);
template<> __device__ inline void fetch4<float>(const float* p, unsigned short* d) {
    float4 v = *reinterpret_cast<const float4*>(p);
    d[0] = f2bf(v.x); d[1] = f2bf(v.y); d[2] = f2bf(v.z); d[3] = f2bf(v.w);
}
template<> __device__ inline void fetch4<unsigned short>(const unsigned short* p, unsigned short* d) {
    *reinterpret_cast<uint2*>(d) = *reinterpret_cast<const uint2*>(p);
}

template<typename T> __device__ inline void store1(T* p, float v);
template<> __device__ inline void store1<float>(float* p, float v) { *p = v; }
template<> __device__ inline void store1<unsigned short>(unsigned short* p, float v) { *p = f2bf(v); }

// C[M,N] = scale * (A[M,K] @ B[N,K]^T) + bias[N]   (round-1 verified)
template<int BM, int BN, int WR, int WC, typename TA, typename TB, typename TO>
__global__ __launch_bounds__(256) void gemm_abt(
    const TA* __restrict__ A, int lda, long long sAb, long long sAh,
    const TB* __restrict__ B, int ldb, long long sBb, long long sBh,
    TO* __restrict__ C, int ldc, long long sCb, long long sCh,
    const float* __restrict__ bias, int K, int H, float scale)
{
    constexpr int LDK = 40;
    constexpr int MF = BM / WR / 16;
    constexpr int NF = BN / WC / 16;
    __shared__ unsigned short lA[BM * LDK];
    __shared__ unsigned short lB[BN * LDK];

    const int tid = threadIdx.x;
    const int z = blockIdx.z;
    const int zb = z / H, zh = z % H;
    const TA* Ap = A + sAb * zb + sAh * zh + (long long)blockIdx.y * BM * lda;
    const TB* Bp = B + sBb * zb + sBh * zh + (long long)blockIdx.x * BN * ldb;
    TO* Cp = C + sCb * zb + sCh * zh + (long long)blockIdx.y * BM * ldc + (long long)blockIdx.x * BN;

    const int wid = tid >> 6, lane = tid & 63;
    const int wr = wid / WC, wc = wid % WC;
    const int r0 = lane & 15;
    const int kq = (lane >> 4) * 8;

    f32x4 acc[MF][NF];
    #pragma unroll
    for (int m = 0; m < MF; ++m)
        #pragma unroll
        for (int n = 0; n < NF; ++n)
            acc[m][n] = f32x4{0.f, 0.f, 0.f, 0.f};

    for (int kt = 0; kt < K; kt += 32) {
        __syncthreads();
        #pragma unroll
        for (int qi = 0; qi < BM * 8 / 256; ++qi) {
            int idx = tid + qi * 256;
            int row = idx >> 3, c4 = idx & 7;
            unsigned short tmp[4];
            fetch4<TA>(Ap + (long long)row * lda + kt + c4 * 4, tmp);
            *reinterpret_cast<uint2*>(&lA[row * LDK + c4 * 4]) = *reinterpret_cast<const uint2*>(tmp);
        }
        #pragma unroll
        for (int qi = 0; qi < BN * 8 / 256; ++qi) {
            int idx = tid + qi * 256;
            int row = idx >> 3, c4 = idx & 7;
            unsigned short tmp[4];
            fetch4<TB>(Bp + (long long)row * ldb + kt + c4 * 4, tmp);
            *reinterpret_cast<uint2*>(&lB[row * LDK + c4 * 4]) = *reinterpret_cast<const uint2*>(tmp);
        }
        __syncthreads();

        bf16x8 af[MF], bfr[NF];
        #pragma unroll
        for (int m = 0; m < MF; ++m)
            af[m] = *reinterpret_cast<const bf16x8*>(&lA[(wr * MF * 16 + m * 16 + r0) * LDK + kq]);
        #pragma unroll
        for (int n = 0; n < NF; ++n)
            bfr[n] = *reinterpret_cast<const bf16x8*>(&lB[(wc * NF * 16 + n * 16 + r0) * LDK + kq]);
        #pragma unroll
        for (int m = 0; m < MF; ++m)
            #pragma unroll
            for (int n = 0; n < NF; ++n)
                acc[m][n] = __builtin_amdgcn_mfma_f32_16x16x32_bf16(af[m], bfr[n], acc[m][n], 0, 0, 0);
    }

    const int cf = lane & 15, rf = (lane >> 4) * 4;
    #pragma unroll
    for (int m = 0; m < MF; ++m) {
        #pragma unroll
        for (int n = 0; n < NF; ++n) {
            int col = wc * NF * 16 + n * 16 + cf;
            float bv = bias ? bias[blockIdx.x * BN + col] : 0.0f;
            #pragma unroll
            for (int j = 0; j < 4; ++j) {
                int row = wr * MF * 16 + m * 16 + rf + j;
                store1<TO>(&Cp[(long long)row * ldc + col], acc[m][n][j] * scale + bv);
            }
        }
    }
}

// vT[(b*NH+h)*64 + d][t] = v_p[b][t][h*64+d]   (round-1 verified)
__global__ __launch_bounds__(256) void transpose_vh(const unsigned short* __restrict__ vp,
                                                    unsigned short* __restrict__ vT)
{
    __shared__ unsigned short tile[64][65];
    const int bh = blockIdx.y;
    const int b = bh >> 4, h = bh & 15;
    const long long t0 = (long long)blockIdx.x * 64;
    const int tid = threadIdx.x;
    #pragma unroll
    for (int kk = 0; kk < 4; ++kk) {
        int l = tid + kk * 256;
        int row = l >> 4, c4 = l & 15;
        const unsigned short* src = vp + ((long long)b * SS + t0 + row) * DM + h * 64 + c4 * 4;
        ushort4 val = *reinterpret_cast<const ushort4*>(src);
        tile[row][c4 * 4 + 0] = val.x;
        tile[row][c4 * 4 + 1] = val.y;
        tile[row][c4 * 4 + 2] = val.z;
        tile[row][c4 * 4 + 3] = val.w;
    }
    __syncthreads();
    #pragma unroll
    for (int kk = 0; kk < 4; ++kk) {
        int l = tid + kk * 256;
        int d = l >> 4, i4 = l & 15;
        ushort4 o;
        o.x = tile[i4 * 4 + 0][d];
        o.y = tile[i4 * 4 + 1][d];
        o.z = tile[i4 * 4 + 2][d];
        o.w = tile[i4 * 4 + 3][d];
        *reinterpret_cast<ushort4*>(vT + ((long long)bh * 64 + d) * SS + t0 + i4 * 4) = o;
    }
}

// Fused attention, strictly phase-separated:
//   P1: S[16][1024] = 0.125 * q.k^T  -> f32 LDS (per-wave disjoint cols, no barriers)
//   barrier
//   P2a: exact softmax stats from LDS; write attnw
//   P2b: PV (raw S @ vh) per-wave d-slice; write cc
// Grid: (SS/16, B*NH), 256 threads = 4 waves.
__global__ __launch_bounds__(256) void fused_attn(
    const unsigned short* __restrict__ qp,   // [B,S,DM] bf16
    const unsigned short* __restrict__ kp,   // [B,S,DM] bf16
    const unsigned short* __restrict__ vT,   // [B*NH*64, S] bf16
    float* __restrict__ attnw,               // [B,NH,S,S] f32
    unsigned short* __restrict__ cc)         // [B,S,DM] bf16
{
    constexpr int LSTR = 1028;               // padded f32 stride
    __shared__ alignas(16) float Sf[16 * LSTR];   // 65.8 KB
    __shared__ float rowM[16];
    __shared__ float rowI[16];

    const int tid = threadIdx.x;
    const int w = tid >> 6;
    const int lane = tid & 63;
    const int lg = lane >> 4;                // 0..3
    const int ln = lane & 15;                // 0..15
    const int z = blockIdx.y, b = z >> 4, h = z & 15;
    const int row0 = blockIdx.x * 16;

    const unsigned short* qbase = qp + ((long long)b * SS + row0) * DM + h * 64;
    const unsigned short* kbase = kp + (long long)b * SS * DM + h * 64;
    const unsigned short* vbase = vT + (long long)z * 64 * SS;

    // ---- Phase 1: S strip ----
    bf16x8 qf[2];
    #pragma unroll
    for (int ks = 0; ks < 2; ++ks)
        qf[ks] = *reinterpret_cast<const bf16x8*>(qbase + (long long)ln * DM + ks * 32 + lg * 8);

    for (int c = 0; c < 8; ++c) {
        const int colbase = c * 128 + w * 32;
        f32x4 sac[2];
        sac[0] = f32x4{0.f, 0.f, 0.f, 0.f};
        sac[1] = f32x4{0.f, 0.f, 0.f, 0.f};
        #pragma unroll
        for (int ks = 0; ks < 2; ++ks) {
            #pragma unroll
            for (int cf2 = 0; cf2 < 2; ++cf2) {
                bf16x8 kf = *reinterpret_cast<const bf16x8*>(
                    kbase + (long long)(colbase + cf2 * 16 + ln) * DM + ks * 32 + lg * 8);
                sac[cf2] = __builtin_amdgcn_mfma_f32_16x16x32_bf16(qf[ks], kf, sac[cf2], 0, 0, 0);
            }
        }
        // D layout (round-1 verified): row=(lane>>4)*4+j, col=lane&15
        #pragma unroll
        for (int cf2 = 0; cf2 < 2; ++cf2)
            #pragma unroll
            for (int j = 0; j < 4; ++j)
                Sf[(lg * 4 + j) * LSTR + colbase + cf2 * 16 + ln] = sac[cf2][j] * 0.125f;
    }
    __syncthreads();

    // ---- Phase 2a: exact softmax stats (16 threads per row) ----
    {
        const int r = tid >> 4;              // 0..15
        const int cb = (tid & 15) * 64;      // 64-col slice
        float mx = -1e30f;
        #pragma unroll
        for (int c4 = 0; c4 < 64; c4 += 4) {
            float4 s = *reinterpret_cast<const float4*>(&Sf[r * LSTR + cb + c4]);
            mx = fmaxf(fmaxf(mx, fmaxf(s.x, s.y)), fmaxf(s.z, s.w));
        }
        #pragma unroll
        for (int o = 1; o < 16; o <<= 1) mx = fmaxf(mx, __shfl_xor(mx, o));
        float se = 0.f;
        #pragma unroll
        for (int c4 = 0; c4 < 64; c4 += 4) {
            float4 s = *reinterpret_cast<const float4*>(&Sf[r * LSTR + cb + c4]);
            se += __expf(s.x - mx) + __expf(s.y - mx) + __expf(s.z - mx) + __expf(s.w - mx);
        }
        #pragma unroll
        for (int o = 1; o < 16; o <<= 1) se += __shfl_xor(se, o);
        if ((tid & 15) == 0) { rowM[r] = mx; rowI[r] = 1.0f / se; }
    }
    __syncthreads();

    // attnw write: row it, 4 cols per thread
    #pragma unroll 4
    for (int it = 0; it < 16; ++it) {
        float mf = rowM[it], inv = rowI[it];
        float4 sv = *reinterpret_cast<const float4*>(&Sf[it * LSTR + tid * 4]);
        float4 o;
        o.x = __expf(sv.x - mf) * inv;
        o.y = __expf(sv.y - mf) * inv;
        o.z = __expf(sv.z - mf) * inv;
        o.w = __expf(sv.w - mf) * inv;
        *reinterpret_cast<float4*>(attnw + ((long long)z * SS + row0 + it) * SS + tid * 4) = o;
    }

    // ---- Phase 2b: PV, wave w owns d in [w*16, w*16+16) ----
    {
        f32x4 pvn = f32x4{0.f, 0.f, 0.f, 0.f};
        const unsigned short* vrow = vbase + (long long)(w * 16 + ln) * SS;
        for (int kk = 0; kk < 32; ++kk) {
            float4 a0 = *reinterpret_cast<const float4*>(&Sf[ln * LSTR + kk * 32 + lg * 8]);
            float4 a1 = *reinterpret_cast<const float4*>(&Sf[ln * LSTR + kk * 32 + lg * 8 + 4]);
            bf16x8 sa;
            sa[0] = (short)f2bf(a0.x); sa[1] = (short)f2bf(a0.y);
            sa[2] = (short)f2bf(a0.z); sa[3] = (short)f2bf(a0.w);
            sa[4] = (short)f2bf(a1.x); sa[5] = (short)f2bf(a1.y);
            sa[6] = (short)f2bf(a1.z); sa[7] = (short)f2bf(a1.w);
            bf16x8 vf = *reinterpret_cast<const bf16x8*>(vrow + kk * 32 + lg * 8);
            pvn = __builtin_amdgcn_mfma_f32_16x16x32_bf16(sa, vf, pvn, 0, 0, 0);
        }
        // D: row = lg*4+j (q-row), col = ln (d within slice)
        #pragma unroll
        for (int j = 0; j < 4; ++j)
            cc[((long long)b * SS + row0 + lg * 4 + j) * DM + h * 64 + w * 16 + ln] = f2bf(pvn[j]);
    }
}

extern "C" void kernel_launch(void* const* d_in, const int* in_sizes, int n_in,
                              void* d_out, int out_size, void* d_ws, size_t ws_size,
                              hipStream_t stream) {
    (void)in_sizes; (void)n_in; (void)out_size; (void)ws_size;
    const float* v    = (const float*)d_in[0];
    const float* q    = (const float*)d_in[2];
    const float* wq_w = (const float*)d_in[3];
    const float* wq_b = (const float*)d_in[4];
    const float* wv_w = (const float*)d_in[5];
    const float* wv_b = (const float*)d_in[6];
    const float* dw   = (const float*)d_in[7];
    const float* db   = (const float*)d_in[8];

    unsigned short* q_p = (unsigned short*)d_ws;
    unsigned short* v_p = q_p + (4 << 20);
    unsigned short* k_p = v_p + (4 << 20);
    unsigned short* vT  = k_p + (4 << 20);
    unsigned short* cc  = vT  + (4 << 20);

    float* out0   = (float*)d_out;
    float* attnw  = out0 + (long long)BS * SS * DM;

    dim3 blk(256);

    gemm_abt<128,128,2,2,float,float,unsigned short><<<dim3(8,32,1),blk,0,stream>>>(
        q, DM, 0, 0, wq_w, DM, 0, 0, q_p, DM, 0, 0, wq_b, DM, 1, 1.0f);
    gemm_abt<128,128,2,2,float,float,unsigned short><<<dim3(8,32,1),blk,0,stream>>>(
        v, DM, 0, 0, wv_w, DM, 0, 0, v_p, DM, 0, 0, wv_b, DM, 1, 1.0f);
    gemm_abt<128,128,2,2,unsigned short,float,unsigned short><<<dim3(8,32,1),blk,0,stream>>>(
        v_p, DM, 0, 0, wv_w, DM, 0, 0, k_p, DM, 0, 0, wv_b, DM, 1, 1.0f);
    transpose_vh<<<dim3(16,64),blk,0,stream>>>(v_p, vT);

    fused_attn<<<dim3(SS/16, BS*NH), blk, 0, stream>>>(q_p, k_p, vT, attnw, cc);

    gemm_abt<128,128,2,2,unsigned short,float,float><<<dim3(8,32,1),blk,0,stream>>>(
        cc, DM, 0, 0, dw, DM, 0, 0, out0, DM, 0, 0, db, DM, 1, 1.0f);
}